// Round 13
// baseline (451.205 us; speedup 1.0000x reference)
//
#include <hip/hip_runtime.h>
#include <hip/hip_bf16.h>
#include <stdint.h>

#define NROWS 32768
#define HDIM  1024
#define CNB   8
#define DCS   128
#define KCB   512
#define ROWS_PB 256

typedef short bf16x8 __attribute__((ext_vector_type(8)));
typedef float f32x4 __attribute__((ext_vector_type(4)));

__device__ __forceinline__ unsigned f2bfu(float x) {
  union { float f; unsigned u; } v; v.f = x;
  return (v.u + 0x7fffu + ((v.u >> 16) & 1u)) >> 16;
}
__device__ __forceinline__ float bfu2f(unsigned short b) {
  union { unsigned u; float f; } v; v.u = ((unsigned)b) << 16;
  return v.f;
}
__device__ __forceinline__ void gload_lds16(const void* g, void* l) {
  __builtin_amdgcn_global_load_lds(
      (const __attribute__((address_space(1))) uint32_t*)g,
      (__attribute__((address_space(3))) uint32_t*)l, 16, 0, 0);
}

// ---- prep: codesB[c] = bf16 image of codes PRE-SCALED by 1/||code||, XOR-swizzled,
//      4 chunks x 32KB per codebook, gl_lds-ready. cn2[c][k] = ||code||^2; zero loss.
// image byte for (k,d): (k>>7)*32768 + (k&127)*256 + ((2d) ^ ((k&7)<<4))
__global__ __launch_bounds__(256) void prep_kernel(
    const float* __restrict__ codes, unsigned short* __restrict__ codesB,
    float* __restrict__ cn2, float* __restrict__ loss_slot) {
  const int c = blockIdx.y;
  const int k0 = blockIdx.x * 64;
  const int t = threadIdx.x;
  const int kl = t & 63;
  const int dq = t >> 6;
  const int k = k0 + kl;
  const float* src = codes + (size_t)c * DCS * KCB + k;
  float vbuf[32];
  float acc = 0.f;
#pragma unroll
  for (int i = 0; i < 32; ++i) {
    float v = src[(size_t)(dq * 32 + i) * KCB];
    vbuf[i] = v;
    acc += v * v;
  }
  __shared__ float red[256];
  red[t] = acc;
  __syncthreads();
  const float s = red[kl] + red[kl + 64] + red[kl + 128] + red[kl + 192];
  const float rn = rsqrtf(s);
  if (t < 64) cn2[c * KCB + k0 + t] = s;

  char* dstbase = (char*)codesB + (size_t)c * 131072 + (size_t)(k >> 7) * 32768 + (k & 127) * 256;
  const unsigned swzk = (unsigned)(k & 7) << 4;
#pragma unroll
  for (int g = 0; g < 4; ++g) {
    unsigned short pk[8];
#pragma unroll
    for (int j = 0; j < 8; ++j) pk[j] = (unsigned short)f2bfu(vbuf[g * 8 + j] * rn);
    unsigned d2 = (unsigned)((dq * 32 + g * 8) * 2);
    *(uint4*)(dstbase + (d2 ^ swzk)) = *(const uint4*)pk;
  }
  if (blockIdx.x == 0 && c == 0 && t == 0) *loss_slot = 0.f;
}

// ---- main: 256 rows x 1 codebook per block; 8 waves x 32 rows (two 16-row sets).
// r6 schedule exactly (same-iteration gumbel prefetch, post-barrier STAGE(i+2));
// each code A-fragment read once from LDS feeds TWO MFMAs (sets A and B),
// halving LDS-read traffic per row and halving barrier count per row.
__global__ __launch_bounds__(512, 2) void vq_kernel(
    const float* __restrict__ hidden, const float* __restrict__ gumbel,
    const unsigned short* __restrict__ codesB, const float* __restrict__ cn2g,
    float* __restrict__ out, float* __restrict__ loss_slot) {
  const int c = blockIdx.y;
  const int nb = blockIdx.x * ROWS_PB;
  const int tid = threadIdx.x;
  const int w = tid >> 6;
  const int l = tid & 63;
  const int l15 = l & 15;
  const int l4 = l >> 4;

  __shared__ char ldsB[2 * 32768];   // 2 x 32KB chunk: [k_local 128][d 128] bf16, swizzled

  const char* cbase = (const char*)codesB + (size_t)c * 131072;

#define STAGE(chunk) { \
    const char* _s = cbase + (size_t)(chunk) * 32768; \
    char* _d = ldsB + ((chunk) & 1) * 32768 + w * 1024; \
    gload_lds16(_s + 0 * 8192 + tid * 16, _d + 0 * 8192); \
    gload_lds16(_s + 1 * 8192 + tid * 16, _d + 1 * 8192); \
    gload_lds16(_s + 2 * 8192 + tid * 16, _d + 2 * 8192); \
    gload_lds16(_s + 3 * 8192 + tid * 16, _d + 3 * 8192); }

  // --- h rows for both sets (issued first = oldest in vmcnt queue)
  const int rowA = nb + w * 32 + l15;
  const int rowB = rowA + 16;
  const float* hpA = hidden + (size_t)rowA * HDIM + c * DCS + l4 * 8;
  const float* hpB = hpA + (size_t)16 * HDIM;
  f32x4 hA0[4], hA1[4], hB0[4], hB1[4];
#pragma unroll
  for (int s = 0; s < 4; ++s) {
    hA0[s] = *(const f32x4*)(hpA + s * 32);
    hA1[s] = *(const f32x4*)(hpA + s * 32 + 4);
    hB0[s] = *(const f32x4*)(hpB + s * 32);
    hB1[s] = *(const f32x4*)(hpB + s * 32 + 4);
  }

  // prologue stages (r6-exact)
  STAGE(0)
  STAGE(1)

  // --- norms + bf16 B-fragments for both row sets
  float hn2A = 0.f, hn2B = 0.f;
#pragma unroll
  for (int s = 0; s < 4; ++s)
#pragma unroll
    for (int j = 0; j < 4; ++j) {
      hn2A += hA0[s][j] * hA0[s][j] + hA1[s][j] * hA1[s][j];
      hn2B += hB0[s][j] * hB0[s][j] + hB1[s][j] * hB1[s][j];
    }
  hn2A += __shfl_xor(hn2A, 16);
  hn2A += __shfl_xor(hn2A, 32);
  hn2B += __shfl_xor(hn2B, 16);
  hn2B += __shfl_xor(hn2B, 32);
  const float hnA = sqrtf(hn2A);
  const float hnB = sqrtf(hn2B);
  const float rhA = hnA > 0.f ? 1.0f / hnA : 0.f;
  const float rhB = hnB > 0.f ? 1.0f / hnB : 0.f;
  bf16x8 afrA[4], afrB[4];
#pragma unroll
  for (int s = 0; s < 4; ++s)
#pragma unroll
    for (int j = 0; j < 4; ++j) {
      afrA[s][j]     = (short)f2bfu(hA0[s][j] * rhA);
      afrA[s][4 + j] = (short)f2bfu(hA1[s][j] * rhA);
      afrB[s][j]     = (short)f2bfu(hB0[s][j] * rhB);
      afrB[s][4 + j] = (short)f2bfu(hB1[s][j] * rhB);
    }

  const float* gbA = gumbel + ((size_t)rowA * CNB + c) * KCB + l4 * 4;
  const float* gbB = gbA + (size_t)16 * CNB * KCB;
  const unsigned swz = (unsigned)(l15 & 7) << 4;

  float bsA = -3.4e38f, baA = 0.f, bsB = -3.4e38f, baB = 0.f;
  int bkA = 0, bkB = 0;

  __syncthreads();   // chunks 0,1 staged

#pragma unroll
  for (int i = 0; i < 4; ++i) {
    const int kc = i * 128;
    const char* buf = ldsB + (i & 1) * 32768;

    // --- same-iteration gumbel prefetch (r6 style); hides under the MFMA phase
    f32x4 gA[8], gB[8];
#pragma unroll
    for (int t = 0; t < 8; ++t) {
      gA[t] = *(const f32x4*)(gbA + kc + t * 16);
      gB[t] = *(const f32x4*)(gbB + kc + t * 16);
    }

    // --- MFMA + scores: each ds_read feeds TWO MFMAs (row sets A and B)
#pragma unroll
    for (int t = 0; t < 8; ++t) {
      const unsigned rowbase = (unsigned)((t * 16 + l15) * 256);
      f32x4 accA = (f32x4){0.f, 0.f, 0.f, 0.f};
      f32x4 accB = (f32x4){0.f, 0.f, 0.f, 0.f};
#pragma unroll
      for (int s = 0; s < 4; ++s) {
        bf16x8 bfr = *(const bf16x8*)(buf + rowbase + (((unsigned)(s * 64 + l4 * 16)) ^ swz));
        accA = __builtin_amdgcn_mfma_f32_16x16x32_bf16(bfr, afrA[s], accA, 0, 0, 0);
        accB = __builtin_amdgcn_mfma_f32_16x16x32_bf16(bfr, afrB[s], accB, 0, 0, 0);
      }
#pragma unroll
      for (int r = 0; r < 4; ++r) {
        const int kf = kc + t * 16 + l4 * 4 + r;
        const float scA = accA[r] + gA[t][r];
        if (scA > bsA) { bsA = scA; bkA = kf; baA = accA[r]; }
        const float scB = accB[r] + gB[t][r];
        if (scB > bsB) { bsB = scB; bkB = kf; baB = accB[r]; }
      }
    }

    if (i < 3) __syncthreads();   // all waves done reading buf[i&1]
    if (i < 2) STAGE(i + 2)       // refill just-freed buffer (r6-exact placement)
  }
#undef STAGE

  // --- cross-lane argmax over the 4 l4 replicas of each h-row (both sets)
#pragma unroll
  for (int m = 16; m <= 32; m <<= 1) {
    float os; int ok; float oa;
    os = __shfl_xor(bsA, m); ok = __shfl_xor(bkA, m); oa = __shfl_xor(baA, m);
    if (os > bsA || (os == bsA && ok < bkA)) { bsA = os; bkA = ok; baA = oa; }
    os = __shfl_xor(bsB, m); ok = __shfl_xor(bkB, m); oa = __shfl_xor(baB, m);
    if (os > bsB || (os == bsB && ok < bkB)) { bsB = os; bkB = ok; baB = oa; }
  }

  // --- epilogue per set: nh = bf16(c/||c||) * ||c||; loss via ||c||^2+||h||^2-2*cos*||h||*||c||
  float lsum = 0.f;
#define EPI(BK, HN2, HN, ROW, BA) { \
    const float c2 = cn2g[c * KCB + (BK)]; \
    const float cn = sqrtf(c2); \
    const float arg = c2 + (HN2) - 2.f * ((BA) * (HN) * cn); \
    if (l4 == 0) lsum += sqrtf(fmaxf(arg, 0.f)); \
    const char* cb = cbase + (size_t)((BK) >> 7) * 32768 + ((BK) & 127) * 256; \
    const unsigned swzk = (unsigned)((BK) & 7) << 4; \
    float* op = out + (size_t)(ROW) * HDIM + c * DCS + l4 * 32; \
    _Pragma("unroll") \
    for (int j = 0; j < 4; ++j) { \
      unsigned d2 = (unsigned)((l4 * 32 + j * 8) * 2); \
      bf16x8 cv = *(const bf16x8*)(cb + (d2 ^ swzk)); \
      f32x4 o0, o1; \
      _Pragma("unroll") \
      for (int e = 0; e < 4; ++e) { \
        o0[e] = bfu2f((unsigned short)cv[e]) * cn; \
        o1[e] = bfu2f((unsigned short)cv[4 + e]) * cn; \
      } \
      *(f32x4*)(op + j * 8) = o0; \
      *(f32x4*)(op + j * 8 + 4) = o1; \
    } }
  EPI(bkA, hn2A, hnA, rowA, baA)
  EPI(bkB, hn2B, hnB, rowB, baB)
#undef EPI

  // --- per-wave loss reduce + one atomic per wave
#pragma unroll
  for (int m = 1; m <= 32; m <<= 1) lsum += __shfl_xor(lsum, m);
  if (l == 0) atomicAdd(loss_slot, lsum * 1.2f);
}

extern "C" void kernel_launch(void* const* d_in, const int* in_sizes, int n_in,
                              void* d_out, int out_size, void* d_ws, size_t ws_size,
                              hipStream_t stream) {
  const float* hidden = (const float*)d_in[0];
  const float* codes  = (const float*)d_in[1];
  const float* gumbel = (const float*)d_in[2];
  float* out = (float*)d_out;
  unsigned short* codesB = (unsigned short*)d_ws;              // 1 MB (8 x 128KB images)
  float* cn2 = (float*)((char*)d_ws + (size_t)CNB * 131072);   // 16 KB
  float* loss_slot = out + (size_t)NROWS * HDIM;

  prep_kernel<<<dim3(8, CNB), 256, 0, stream>>>(codes, codesB, cn2, loss_slot);
  vq_kernel<<<dim3(NROWS / ROWS_PB, CNB), 512, 0, stream>>>(hidden, gumbel, codesB, cn2, out, loss_slot);
}

// Round 14
// 240.853 us; speedup vs baseline: 1.8734x; 1.8734x over previous
//
#include <hip/hip_runtime.h>
#include <hip/hip_bf16.h>
#include <stdint.h>

#define NROWS 32768
#define HDIM  1024
#define CNB   8
#define DCS   128
#define KCB   512
#define ROWS_PB 256

typedef short bf16x8 __attribute__((ext_vector_type(8)));
typedef float f32x4 __attribute__((ext_vector_type(4)));
typedef float f32x16 __attribute__((ext_vector_type(16)));

__device__ __forceinline__ unsigned f2bfu(float x) {
  union { float f; unsigned u; } v; v.f = x;
  return (v.u + 0x7fffu + ((v.u >> 16) & 1u)) >> 16;
}
__device__ __forceinline__ float bfu2f(unsigned short b) {
  union { unsigned u; float f; } v; v.u = ((unsigned)b) << 16;
  return v.f;
}
__device__ __forceinline__ void gload_lds16(const void* g, void* l) {
  __builtin_amdgcn_global_load_lds(
      (const __attribute__((address_space(1))) uint32_t*)g,
      (__attribute__((address_space(3))) uint32_t*)l, 16, 0, 0);
}

// ---- prep (UNCHANGED from r6): codesB[c] = bf16 image pre-scaled by 1/||code||,
//      XOR-swizzled, 4 chunks x 32KB per codebook. cn2[c][k] = ||code||^2; zero loss.
// image byte for (k,d): (k>>7)*32768 + (k&127)*256 + ((2d) ^ ((k&7)<<4))
__global__ __launch_bounds__(256) void prep_kernel(
    const float* __restrict__ codes, unsigned short* __restrict__ codesB,
    float* __restrict__ cn2, float* __restrict__ loss_slot) {
  const int c = blockIdx.y;
  const int k0 = blockIdx.x * 64;
  const int t = threadIdx.x;
  const int kl = t & 63;
  const int dq = t >> 6;
  const int k = k0 + kl;
  const float* src = codes + (size_t)c * DCS * KCB + k;
  float vbuf[32];
  float acc = 0.f;
#pragma unroll
  for (int i = 0; i < 32; ++i) {
    float v = src[(size_t)(dq * 32 + i) * KCB];
    vbuf[i] = v;
    acc += v * v;
  }
  __shared__ float red[256];
  red[t] = acc;
  __syncthreads();
  const float s = red[kl] + red[kl + 64] + red[kl + 128] + red[kl + 192];
  const float rn = rsqrtf(s);
  if (t < 64) cn2[c * KCB + k0 + t] = s;

  char* dstbase = (char*)codesB + (size_t)c * 131072 + (size_t)(k >> 7) * 32768 + (k & 127) * 256;
  const unsigned swzk = (unsigned)(k & 7) << 4;
#pragma unroll
  for (int g = 0; g < 4; ++g) {
    unsigned short pk[8];
#pragma unroll
    for (int j = 0; j < 8; ++j) pk[j] = (unsigned short)f2bfu(vbuf[g * 8 + j] * rn);
    unsigned d2 = (unsigned)((dq * 32 + g * 8) * 2);
    *(uint4*)(dstbase + (d2 ^ swzk)) = *(const uint4*)pk;
  }
  if (blockIdx.x == 0 && c == 0 && t == 0) *loss_slot = 0.f;
}

// ---- main: 256 rows x 1 codebook per block; 8 waves x 32 rows via 32x32x16 MFMA.
// r6 schedule exactly; per-row LDS traffic and barrier count halved vs r6.
// A (codes, LDS): lane row=l&31, k=(l>>5)*8+j. B (h, regs): col=l&31, k=(l>>5)*8+j.
// D: col(h-row)=lane&31, code=(reg&3)+8*(reg>>2)+4*(lane>>5).
__global__ __launch_bounds__(512, 2) void vq_kernel(
    const float* __restrict__ hidden, const float* __restrict__ gumbel,
    const unsigned short* __restrict__ codesB, const float* __restrict__ cn2g,
    float* __restrict__ out, float* __restrict__ loss_slot) {
  const int c = blockIdx.y;
  const int nb = blockIdx.x * ROWS_PB;
  const int tid = threadIdx.x;
  const int w = tid >> 6;
  const int l = tid & 63;
  const int l31 = l & 31;
  const int hi = l >> 5;

  __shared__ char ldsB[2 * 32768];   // 2 x 32KB chunk: [k_local 128][d 128] bf16, swizzled

  const char* cbase = (const char*)codesB + (size_t)c * 131072;

#define STAGE(chunk) { \
    const char* _s = cbase + (size_t)(chunk) * 32768; \
    char* _d = ldsB + ((chunk) & 1) * 32768 + w * 1024; \
    gload_lds16(_s + 0 * 8192 + tid * 16, _d + 0 * 8192); \
    gload_lds16(_s + 1 * 8192 + tid * 16, _d + 1 * 8192); \
    gload_lds16(_s + 2 * 8192 + tid * 16, _d + 2 * 8192); \
    gload_lds16(_s + 3 * 8192 + tid * 16, _d + 3 * 8192); }

  // --- h row: lane owns row (l&31), d-half hi: d = s*16 + hi*8 + (0..7)
  const int row = nb + w * 32 + l31;
  const float* hp = hidden + (size_t)row * HDIM + c * DCS + hi * 8;
  f32x4 hr0[8], hr1[8];
#pragma unroll
  for (int s = 0; s < 8; ++s) {
    hr0[s] = *(const f32x4*)(hp + s * 16);
    hr1[s] = *(const f32x4*)(hp + s * 16 + 4);
  }

  // prologue stages (r6-exact)
  STAGE(0)
  STAGE(1)

  // --- norm: each lane sums its 64 d-values; pair (l, l^32) completes the row
  float hn2 = 0.f;
#pragma unroll
  for (int s = 0; s < 8; ++s)
#pragma unroll
    for (int j = 0; j < 4; ++j) hn2 += hr0[s][j] * hr0[s][j] + hr1[s][j] * hr1[s][j];
  hn2 += __shfl_xor(hn2, 32);
  const float hnorm = sqrtf(hn2);
  const float rh = hnorm > 0.f ? 1.0f / hnorm : 0.f;
  bf16x8 afr[8];
#pragma unroll
  for (int s = 0; s < 8; ++s)
#pragma unroll
    for (int j = 0; j < 4; ++j) {
      afr[s][j]     = (short)f2bfu(hr0[s][j] * rh);
      afr[s][4 + j] = (short)f2bfu(hr1[s][j] * rh);
    }

  const float* gb = gumbel + ((size_t)row * CNB + c) * KCB + hi * 4;
  const unsigned swz = (unsigned)(l & 7) << 4;

  float bs = -3.4e38f, ba = 0.f;
  int bk = 0;

  __syncthreads();   // chunks 0,1 staged

#define GLOAD(T) { \
    _Pragma("unroll") \
    for (int q = 0; q < 4; ++q) g[T][q] = *(const f32x4*)(gb + kc + (T) * 32 + q * 8); }
#define MFMAT(ACC, T) { \
    ACC = (f32x16){0.f,0.f,0.f,0.f,0.f,0.f,0.f,0.f,0.f,0.f,0.f,0.f,0.f,0.f,0.f,0.f}; \
    _Pragma("unroll") \
    for (int s = 0; s < 8; ++s) { \
      bf16x8 bfr = *(const bf16x8*)(buf + (unsigned)(((T) * 32 + l31) * 256) + \
                     (((unsigned)(s * 32 + hi * 16)) ^ swz)); \
      ACC = __builtin_amdgcn_mfma_f32_32x32x16_bf16(bfr, afr[s], ACC, 0, 0, 0); \
    } }
#define SCORET(ACC, T) { \
    _Pragma("unroll") \
    for (int r = 0; r < 16; ++r) { \
      const int kf = kc + (T) * 32 + (r & 3) + 8 * (r >> 2) + 4 * hi; \
      const float sc = ACC[r] + g[T][r >> 2][r & 3]; \
      if (sc > bs) { bs = sc; bk = kf; ba = ACC[r]; } \
    } }

#pragma unroll
  for (int i = 0; i < 4; ++i) {
    const int kc = i * 128;
    const char* buf = ldsB + (i & 1) * 32768;
    f32x4 g[4][4];
    f32x16 accA, accB;

    GLOAD(0) GLOAD(1)          // tiles 0,1 gumbel in flight under 2 MFMA tiles
    MFMAT(accA, 0)
    MFMAT(accB, 1)
    SCORET(accA, 0)
    GLOAD(2)
    MFMAT(accA, 2)
    SCORET(accB, 1)
    GLOAD(3)
    MFMAT(accB, 3)
    SCORET(accA, 2)
    SCORET(accB, 3)

    if (i < 3) __syncthreads();   // all waves done reading buf[i&1]
    if (i < 2) STAGE(i + 2)       // refill just-freed buffer (r6-exact placement)
  }
#undef GLOAD
#undef MFMAT
#undef SCORET
#undef STAGE

  // --- cross-lane argmax: pair (l, l^32) holds the row's two disjoint k-sets
  {
    float os = __shfl_xor(bs, 32);
    int ok = __shfl_xor(bk, 32);
    float oa = __shfl_xor(ba, 32);
    if (os > bs || (os == bs && ok < bk)) { bs = os; bk = ok; ba = oa; }
  }

  // --- epilogue: nh = bf16(c/||c||) * ||c||; loss via ||c||^2+||h||^2-2*cos*||h||*||c||
  const float c2 = cn2g[c * KCB + bk];
  const float cn = sqrtf(c2);
  const float arg = c2 + hn2 - 2.f * (ba * hnorm * cn);
  float lsum = (hi == 0) ? sqrtf(fmaxf(arg, 0.f)) : 0.f;

  const char* cb = cbase + (size_t)(bk >> 7) * 32768 + (bk & 127) * 256;
  const unsigned swzk = (unsigned)(bk & 7) << 4;
  float* op = out + (size_t)row * HDIM + c * DCS + hi * 64;
#pragma unroll
  for (int j = 0; j < 8; ++j) {
    unsigned d2 = (unsigned)(hi * 128 + j * 16);
    bf16x8 cv = *(const bf16x8*)(cb + (d2 ^ swzk));
    f32x4 o0, o1;
#pragma unroll
    for (int e = 0; e < 4; ++e) {
      o0[e] = bfu2f((unsigned short)cv[e]) * cn;
      o1[e] = bfu2f((unsigned short)cv[4 + e]) * cn;
    }
    *(f32x4*)(op + j * 8) = o0;
    *(f32x4*)(op + j * 8 + 4) = o1;
  }

  // --- per-wave loss reduce + one atomic per wave
#pragma unroll
  for (int m = 1; m <= 32; m <<= 1) lsum += __shfl_xor(lsum, m);
  if (l == 0) atomicAdd(loss_slot, lsum * 1.2f);
}

extern "C" void kernel_launch(void* const* d_in, const int* in_sizes, int n_in,
                              void* d_out, int out_size, void* d_ws, size_t ws_size,
                              hipStream_t stream) {
  const float* hidden = (const float*)d_in[0];
  const float* codes  = (const float*)d_in[1];
  const float* gumbel = (const float*)d_in[2];
  float* out = (float*)d_out;
  unsigned short* codesB = (unsigned short*)d_ws;              // 1 MB (8 x 128KB images)
  float* cn2 = (float*)((char*)d_ws + (size_t)CNB * 131072);   // 16 KB
  float* loss_slot = out + (size_t)NROWS * HDIM;

  prep_kernel<<<dim3(8, CNB), 256, 0, stream>>>(codes, codesB, cn2, loss_slot);
  vq_kernel<<<dim3(NROWS / ROWS_PB, CNB), 512, 0, stream>>>(hidden, gumbel, codesB, cn2, out, loss_slot);
}